// Round 2
// baseline (287.989 us; speedup 1.0000x reference)
//
#include <hip/hip_runtime.h>

constexpr int HWs = 4096;   // 64*64 spatial

// ---------------------------------------------------------------------------
// Prep: fold BN into w1 (transposed), transpose wp. 81984 elements.
// ---------------------------------------------------------------------------
__global__ __launch_bounds__(256) void prep_k(
    const float* __restrict__ w1, const float* __restrict__ gamma,
    const float* __restrict__ beta, const float* __restrict__ mean,
    const float* __restrict__ var, const float* __restrict__ wp,
    float* __restrict__ w1t, float* __restrict__ b1, float* __restrict__ wpt)
{
    int idx = blockIdx.x * 256 + threadIdx.x;
    if (idx < 16384) {                       // w1t[c][o] = w1[o][c]*scale[o]
        int c = idx >> 6, o = idx & 63;
        float s = gamma[o] * rsqrtf(var[o] + 1e-5f);
        w1t[idx] = w1[o * 256 + c] * s;
    } else if (idx < 16448) {                // b1[o] = beta - mean*scale
        int o = idx - 16384;
        float s = gamma[o] * rsqrtf(var[o] + 1e-5f);
        b1[o] = beta[o] - mean[o] * s;
    } else if (idx < 81984) {                // wpt[c][o] = wp[o][c]
        int i = idx - 16448;
        int c = i >> 8, o = i & 255;
        wpt[i] = wp[o * 256 + c];
    }
}

// ---------------------------------------------------------------------------
// 64x64-tile GEMM (stage 1 only): C[b][m][hw] = sum_k At[k][m]*Bm[b][k][hw]
// ---------------------------------------------------------------------------
template<bool RELU, bool BIAS>
__global__ __launch_bounds__(256) void gemm_k(
    const float* __restrict__ At, const float* __restrict__ Bm,
    const float* __restrict__ bias, float* __restrict__ Cout,
    int K, int Mtot, int tilesPerBatch)
{
    const int t = threadIdx.x;
    const int bt = blockIdx.x;
    const int batch = bt / tilesPerBatch;
    const int n0 = (bt - batch * tilesPerBatch) * 64;
    const int m0 = blockIdx.y * 64;
    const float* Bb = Bm + (size_t)batch * K * HWs;
    float* Cb = Cout + (size_t)batch * Mtot * HWs;

    __shared__ float As[64][64];
    __shared__ float Bs[64][64];

    const int og = t >> 4, pg = t & 15;
    float acc[4][4];
#pragma unroll
    for (int i = 0; i < 4; ++i)
#pragma unroll
        for (int j = 0; j < 4; ++j) acc[i][j] = 0.f;

    for (int kc = 0; kc < K; kc += 64) {
#pragma unroll
        for (int r = 0; r < 16; ++r) {
            int idx = t + r * 256;
            int kk = idx >> 6, col = idx & 63;
            int m = m0 + col;
            As[kk][col] = (m < Mtot) ? At[(size_t)(kc + kk) * Mtot + m] : 0.f;
            Bs[kk][col] = Bb[(size_t)(kc + kk) * HWs + n0 + col];
        }
        __syncthreads();
#pragma unroll 8
        for (int k = 0; k < 64; ++k) {
            const float4 av = *reinterpret_cast<const float4*>(&As[k][og * 4]);
            const float4 bv = *reinterpret_cast<const float4*>(&Bs[k][pg * 4]);
            acc[0][0] += av.x * bv.x; acc[0][1] += av.x * bv.y;
            acc[0][2] += av.x * bv.z; acc[0][3] += av.x * bv.w;
            acc[1][0] += av.y * bv.x; acc[1][1] += av.y * bv.y;
            acc[1][2] += av.y * bv.z; acc[1][3] += av.y * bv.w;
            acc[2][0] += av.z * bv.x; acc[2][1] += av.z * bv.y;
            acc[2][2] += av.z * bv.z; acc[2][3] += av.z * bv.w;
            acc[3][0] += av.w * bv.x; acc[3][1] += av.w * bv.y;
            acc[3][2] += av.w * bv.z; acc[3][3] += av.w * bv.w;
        }
        __syncthreads();
    }

#pragma unroll
    for (int i = 0; i < 4; ++i) {
        int m = m0 + og * 4 + i;
        if (m < Mtot) {
            float bv = BIAS ? bias[m] : 0.f;
            float4 o4;
            o4.x = acc[i][0] + bv; o4.y = acc[i][1] + bv;
            o4.z = acc[i][2] + bv; o4.w = acc[i][3] + bv;
            if (RELU) {
                o4.x = fmaxf(o4.x, 0.f); o4.y = fmaxf(o4.y, 0.f);
                o4.z = fmaxf(o4.z, 0.f); o4.w = fmaxf(o4.w, 0.f);
            }
            *reinterpret_cast<float4*>(&Cb[(size_t)m * HWs + n0 + pg * 4]) = o4;
        }
    }
}

// ---------------------------------------------------------------------------
// Fused weight-gen + involution. Block = (16x16 tile, group, batch).
// Each thread owns one pixel: y[0:64] in registers, w2 group-slice in LDS,
// computes wt[kk] on the fly (64-FMA dot, 4 partials) and applies it to the
// 16 channels from the x-patch LDS. No 51 MB wt intermediate.
// ---------------------------------------------------------------------------
__global__ __launch_bounds__(256) void fused_inv_k(
    const float* __restrict__ x, const float* __restrict__ y,
    const float* __restrict__ w2, const float* __restrict__ b2,
    float* __restrict__ out)
{
    const int t = threadIdx.x;
    const int tile = blockIdx.x;       // 16 tiles (4x4 of 16x16)
    const int g = blockIdx.y;          // 16 groups
    const int b = blockIdx.z;          // 4 batches
    const int ty0 = (tile >> 2) * 16, tx0 = (tile & 3) * 16;

    __shared__ float xs[484 * 20];     // 38720 B, [spatial 22x22][16ch+4pad]
    __shared__ float w2s[49][64];      // 12544 B
    __shared__ float b2s[49];

    // stage x patch for this group's 16 channels
    const float* xb = x + (size_t)(b * 256 + g * 16) * HWs;
    for (int idx = t; idx < 484 * 16; idx += 256) {
        int ci = idx / 484;
        int sp = idx - ci * 484;
        int sy = sp / 22, sx = sp - sy * 22;
        int gy = ty0 + sy - 3, gx = tx0 + sx - 3;
        float v = 0.f;
        if ((unsigned)gy < 64u && (unsigned)gx < 64u)
            v = xb[(size_t)ci * HWs + gy * 64 + gx];
        xs[sp * 20 + ci] = v;
    }
    // stage w2 rows for this group (row-major contiguous 49x64)
    const float* w2g = w2 + (size_t)g * 49 * 64;
    for (int idx = t; idx < 49 * 64; idx += 256)
        w2s[idx >> 6][idx & 63] = w2g[idx];
    if (t < 49) b2s[t] = b2[g * 49 + t];

    // this thread's pixel: load y[b][0:64][pix] into registers (coalesced)
    const int py = t >> 4, px = t & 15;
    const int pix = (ty0 + py) * 64 + tx0 + px;
    float yreg[64];
    const float* yb = y + (size_t)b * 64 * HWs + pix;
#pragma unroll
    for (int k = 0; k < 64; ++k) yreg[k] = yb[(size_t)k * HWs];

    __syncthreads();

    float acc[16];
#pragma unroll
    for (int i = 0; i < 16; ++i) acc[i] = 0.f;

    for (int dy = 0; dy < 7; ++dy) {
#pragma unroll
        for (int dx = 0; dx < 7; ++dx) {
            const int kk = dy * 7 + dx;
            // wt[kk] for this pixel: dot(w2s[kk][:], yreg[:]) + b2
            float wv0 = 0.f, wv1 = 0.f, wv2 = 0.f, wv3 = 0.f;
#pragma unroll
            for (int k4 = 0; k4 < 16; ++k4) {
                const float4 w4 = *reinterpret_cast<const float4*>(&w2s[kk][k4 * 4]);
                wv0 += w4.x * yreg[k4 * 4 + 0];
                wv1 += w4.y * yreg[k4 * 4 + 1];
                wv2 += w4.z * yreg[k4 * 4 + 2];
                wv3 += w4.w * yreg[k4 * 4 + 3];
            }
            const float wv = b2s[kk] + ((wv0 + wv1) + (wv2 + wv3));
            const float* xrow = &xs[((py + dy) * 22 + px + dx) * 20];
#pragma unroll
            for (int c4 = 0; c4 < 4; ++c4) {
                const float4 xv = *reinterpret_cast<const float4*>(&xrow[c4 * 4]);
                acc[c4 * 4 + 0] += wv * xv.x;
                acc[c4 * 4 + 1] += wv * xv.y;
                acc[c4 * 4 + 2] += wv * xv.z;
                acc[c4 * 4 + 3] += wv * xv.w;
            }
        }
    }

    float* ob = out + (size_t)(b * 256 + g * 16) * HWs + pix;
#pragma unroll
    for (int ci = 0; ci < 16; ++ci)
        ob[(size_t)ci * HWs] = acc[ci];
}

// ---------------------------------------------------------------------------
// Final GEMM: 128x128 tile, 8x8 per thread, KC=32, double-buffered LDS.
// out[b][m][hw] = sum_k wpt[k][m] * inv[b][k][hw]   (K = M = 256)
// ---------------------------------------------------------------------------
__global__ __launch_bounds__(256) void gemm128_k(
    const float* __restrict__ At,   // [256][256] = wpt (k-major)
    const float* __restrict__ Bm,   // [b][256][4096]
    float* __restrict__ Cout)
{
    const int t = threadIdx.x;
    const int nt = blockIdx.x;         // 0..127 : 32 n-tiles x 4 batches
    const int batch = nt >> 5;
    const int n0 = (nt & 31) * 128;
    const int m0 = blockIdx.y * 128;
    const float* Bb = Bm + (size_t)batch * 256 * HWs;
    float* Cb = Cout + (size_t)batch * 256 * HWs;

    __shared__ float As[2][32][128];   // 32 KB
    __shared__ float Bs[2][32][128];   // 32 KB

    const int mg = t >> 4, ng = t & 15;

    float acc[8][8];
#pragma unroll
    for (int i = 0; i < 8; ++i)
#pragma unroll
        for (int j = 0; j < 8; ++j) acc[i][j] = 0.f;

    float4 ra[4], rb[4];
#pragma unroll
    for (int r = 0; r < 4; ++r) {
        int fid = t + r * 256; int row = fid >> 5, c4 = (fid & 31) * 4;
        ra[r] = *reinterpret_cast<const float4*>(&At[(size_t)row * 256 + m0 + c4]);
        rb[r] = *reinterpret_cast<const float4*>(&Bb[(size_t)row * HWs + n0 + c4]);
    }
#pragma unroll
    for (int r = 0; r < 4; ++r) {
        int fid = t + r * 256; int row = fid >> 5, c4 = (fid & 31) * 4;
        *reinterpret_cast<float4*>(&As[0][row][c4]) = ra[r];
        *reinterpret_cast<float4*>(&Bs[0][row][c4]) = rb[r];
    }
    __syncthreads();

    for (int c = 0; c < 8; ++c) {
        const int cur = c & 1, nxt = cur ^ 1;
        if (c < 7) {
            const int kc = (c + 1) * 32;
#pragma unroll
            for (int r = 0; r < 4; ++r) {
                int fid = t + r * 256; int row = fid >> 5, c4 = (fid & 31) * 4;
                ra[r] = *reinterpret_cast<const float4*>(&At[(size_t)(kc + row) * 256 + m0 + c4]);
                rb[r] = *reinterpret_cast<const float4*>(&Bb[(size_t)(kc + row) * HWs + n0 + c4]);
            }
        }
#pragma unroll
        for (int k = 0; k < 32; ++k) {
            const float4 a0 = *reinterpret_cast<const float4*>(&As[cur][k][mg * 4]);
            const float4 a1 = *reinterpret_cast<const float4*>(&As[cur][k][64 + mg * 4]);
            const float4 b0 = *reinterpret_cast<const float4*>(&Bs[cur][k][ng * 4]);
            const float4 b1 = *reinterpret_cast<const float4*>(&Bs[cur][k][64 + ng * 4]);
            const float am[8] = {a0.x, a0.y, a0.z, a0.w, a1.x, a1.y, a1.z, a1.w};
            const float bn[8] = {b0.x, b0.y, b0.z, b0.w, b1.x, b1.y, b1.z, b1.w};
#pragma unroll
            for (int i = 0; i < 8; ++i)
#pragma unroll
                for (int j = 0; j < 8; ++j) acc[i][j] += am[i] * bn[j];
        }
        if (c < 7) {
#pragma unroll
            for (int r = 0; r < 4; ++r) {
                int fid = t + r * 256; int row = fid >> 5, c4 = (fid & 31) * 4;
                *reinterpret_cast<float4*>(&As[nxt][row][c4]) = ra[r];
                *reinterpret_cast<float4*>(&Bs[nxt][row][c4]) = rb[r];
            }
            __syncthreads();
        }
    }

#pragma unroll
    for (int i = 0; i < 8; ++i) {
        int m = m0 + ((i < 4) ? (mg * 4 + i) : (64 + mg * 4 + (i - 4)));
        float* crow = &Cb[(size_t)m * HWs + n0];
        float4 o0 = {acc[i][0], acc[i][1], acc[i][2], acc[i][3]};
        float4 o1 = {acc[i][4], acc[i][5], acc[i][6], acc[i][7]};
        *reinterpret_cast<float4*>(&crow[ng * 4]) = o0;
        *reinterpret_cast<float4*>(&crow[64 + ng * 4]) = o1;
    }
}

// ---------------------------------------------------------------------------
extern "C" void kernel_launch(void* const* d_in, const int* in_sizes, int n_in,
                              void* d_out, int out_size, void* d_ws, size_t ws_size,
                              hipStream_t stream)
{
    const float* x     = (const float*)d_in[0];
    const float* w1    = (const float*)d_in[1];
    const float* gamma = (const float*)d_in[2];
    const float* beta  = (const float*)d_in[3];
    const float* mean  = (const float*)d_in[4];
    const float* var   = (const float*)d_in[5];
    const float* w2    = (const float*)d_in[6];
    const float* b2    = (const float*)d_in[7];
    const float* wp    = (const float*)d_in[8];
    float* out = (float*)d_out;
    float* ws  = (float*)d_ws;

    // workspace layout (floats)
    float* w1t = ws;                 // 16384
    float* b1  = ws + 16384;         // 64
    float* wpt = ws + 16448;         // 65536
    float* y   = ws + 81984;         // 4*64*4096  = 1,048,576
    float* inv = ws + 1130560;       // 4*256*4096 = 4,194,304
                                     // total 5,324,864 floats = 21.3 MB

    prep_k<<<321, 256, 0, stream>>>(w1, gamma, beta, mean, var, wp, w1t, b1, wpt);
    // y = relu(BN(w1 @ x))
    gemm_k<true, true><<<dim3(256, 1), 256, 0, stream>>>(w1t, x, b1, y, 256, 64, 64);
    // fused: wt = w2 @ y + b2 ; inv = involution(x, wt)
    fused_inv_k<<<dim3(16, 16, 4), 256, 0, stream>>>(x, y, w2, b2, inv);
    // out = wp @ inv
    gemm128_k<<<dim3(128, 2), 256, 0, stream>>>(wpt, inv, out);
}

// Round 3
// 156.991 us; speedup vs baseline: 1.8344x; 1.8344x over previous
//
#include <hip/hip_runtime.h>

constexpr int HWs = 4096;   // 64*64 spatial

// ---------------------------------------------------------------------------
// Prep: fold BN into w1 (transposed), transpose w2 and wp.
// ---------------------------------------------------------------------------
__global__ __launch_bounds__(256) void prep_k(
    const float* __restrict__ w1, const float* __restrict__ gamma,
    const float* __restrict__ beta, const float* __restrict__ mean,
    const float* __restrict__ var, const float* __restrict__ w2,
    const float* __restrict__ wp,
    float* __restrict__ w1t, float* __restrict__ b1,
    float* __restrict__ w2t, float* __restrict__ wpt)
{
    int idx = blockIdx.x * 256 + threadIdx.x;
    if (idx < 16384) {                       // w1t[c][o] = w1[o][c]*scale[o]
        int c = idx >> 6, o = idx & 63;
        float s = gamma[o] * rsqrtf(var[o] + 1e-5f);
        w1t[idx] = w1[o * 256 + c] * s;
    } else if (idx < 16448) {                // b1[o] = beta - mean*scale
        int o = idx - 16384;
        float s = gamma[o] * rsqrtf(var[o] + 1e-5f);
        b1[o] = beta[o] - mean[o] * s;
    } else if (idx < 66624) {                // w2t[k][m] = w2[m][k]
        int i = idx - 16448;
        int k = i / 784, m = i - k * 784;
        w2t[i] = w2[m * 64 + k];
    } else if (idx < 132160) {               // wpt[c][o] = wp[o][c]
        int i = idx - 66624;
        int c = i >> 8, o = i & 255;
        wpt[i] = wp[o * 256 + c];
    }
}

// ---------------------------------------------------------------------------
// 64x64-tile GEMM (stage 1): C[b][m][hw] = sum_k At[k][m]*Bm[b][k][hw]
// ---------------------------------------------------------------------------
template<bool RELU, bool BIAS>
__global__ __launch_bounds__(256) void gemm_k(
    const float* __restrict__ At, const float* __restrict__ Bm,
    const float* __restrict__ bias, float* __restrict__ Cout,
    int K, int Mtot, int tilesPerBatch)
{
    const int t = threadIdx.x;
    const int bt = blockIdx.x;
    const int batch = bt / tilesPerBatch;
    const int n0 = (bt - batch * tilesPerBatch) * 64;
    const int m0 = blockIdx.y * 64;
    const float* Bb = Bm + (size_t)batch * K * HWs;
    float* Cb = Cout + (size_t)batch * Mtot * HWs;

    __shared__ float As[64][64];
    __shared__ float Bs[64][64];

    const int og = t >> 4, pg = t & 15;
    float acc[4][4];
#pragma unroll
    for (int i = 0; i < 4; ++i)
#pragma unroll
        for (int j = 0; j < 4; ++j) acc[i][j] = 0.f;

    for (int kc = 0; kc < K; kc += 64) {
#pragma unroll
        for (int r = 0; r < 16; ++r) {
            int idx = t + r * 256;
            int kk = idx >> 6, col = idx & 63;
            int m = m0 + col;
            As[kk][col] = (m < Mtot) ? At[(size_t)(kc + kk) * Mtot + m] : 0.f;
            Bs[kk][col] = Bb[(size_t)(kc + kk) * HWs + n0 + col];
        }
        __syncthreads();
#pragma unroll 8
        for (int k = 0; k < 64; ++k) {
            const float4 av = *reinterpret_cast<const float4*>(&As[k][og * 4]);
            const float4 bv = *reinterpret_cast<const float4*>(&Bs[k][pg * 4]);
            acc[0][0] += av.x * bv.x; acc[0][1] += av.x * bv.y;
            acc[0][2] += av.x * bv.z; acc[0][3] += av.x * bv.w;
            acc[1][0] += av.y * bv.x; acc[1][1] += av.y * bv.y;
            acc[1][2] += av.y * bv.z; acc[1][3] += av.y * bv.w;
            acc[2][0] += av.z * bv.x; acc[2][1] += av.z * bv.y;
            acc[2][2] += av.z * bv.z; acc[2][3] += av.z * bv.w;
            acc[3][0] += av.w * bv.x; acc[3][1] += av.w * bv.y;
            acc[3][2] += av.w * bv.z; acc[3][3] += av.w * bv.w;
        }
        __syncthreads();
    }

#pragma unroll
    for (int i = 0; i < 4; ++i) {
        int m = m0 + og * 4 + i;
        if (m < Mtot) {
            float bv = BIAS ? bias[m] : 0.f;
            float4 o4;
            o4.x = acc[i][0] + bv; o4.y = acc[i][1] + bv;
            o4.z = acc[i][2] + bv; o4.w = acc[i][3] + bv;
            if (RELU) {
                o4.x = fmaxf(o4.x, 0.f); o4.y = fmaxf(o4.y, 0.f);
                o4.z = fmaxf(o4.z, 0.f); o4.w = fmaxf(o4.w, 0.f);
            }
            *reinterpret_cast<float4*>(&Cb[(size_t)m * HWs + n0 + pg * 4]) = o4;
        }
    }
}

// ---------------------------------------------------------------------------
// 128x128-tile GEMM, 8x8 per thread, KC=16, single LDS buffer, loads issued
// before compute. All FMA constant-indexed (no spillable local arrays).
// C[b][m][hw] = sum_k At[k][m]*Bm[b][k][hw]
// ---------------------------------------------------------------------------
#define ROW8(I, AX) \
    acc[I][0] += AX * b0.x; acc[I][1] += AX * b0.y; \
    acc[I][2] += AX * b0.z; acc[I][3] += AX * b0.w; \
    acc[I][4] += AX * b1.x; acc[I][5] += AX * b1.y; \
    acc[I][6] += AX * b1.z; acc[I][7] += AX * b1.w;

template<bool BIAS>
__global__ __launch_bounds__(256) void gemm128_k(
    const float* __restrict__ At,   // [K][Mtot] k-major
    const float* __restrict__ Bm,   // [b][K][4096]
    const float* __restrict__ bias,
    float* __restrict__ Cout,       // [b][Mtot][4096]
    int K, int Mtot)
{
    const int t = threadIdx.x;
    const int nt = blockIdx.x;         // 32 n-tiles x 4 batches
    const int batch = nt >> 5;
    const int n0 = (nt & 31) * 128;
    const int m0 = blockIdx.y * 128;
    const float* Bb = Bm + (size_t)batch * K * HWs;
    float* Cb = Cout + (size_t)batch * Mtot * HWs;

    __shared__ float As[16][128];   // 8 KB
    __shared__ float Bs[16][128];   // 8 KB

    const int mg = t >> 4, ng = t & 15;
    const int lrow = t >> 5, lc4 = (t & 31) * 4;   // load coords (2 rows/thread)

    float acc[8][8];
#pragma unroll
    for (int i = 0; i < 8; ++i)
#pragma unroll
        for (int j = 0; j < 8; ++j) acc[i][j] = 0.f;

    float4 ra0, ra1, rb0, rb1;
    // prologue: load chunk 0
    {
        const int ma = m0 + lc4;
        ra0 = (ma < Mtot) ? *reinterpret_cast<const float4*>(&At[(size_t)lrow * Mtot + ma])
                          : float4{0.f, 0.f, 0.f, 0.f};
        ra1 = (ma < Mtot) ? *reinterpret_cast<const float4*>(&At[(size_t)(lrow + 8) * Mtot + ma])
                          : float4{0.f, 0.f, 0.f, 0.f};
        rb0 = *reinterpret_cast<const float4*>(&Bb[(size_t)lrow * HWs + n0 + lc4]);
        rb1 = *reinterpret_cast<const float4*>(&Bb[(size_t)(lrow + 8) * HWs + n0 + lc4]);
    }
    *reinterpret_cast<float4*>(&As[lrow][lc4]) = ra0;
    *reinterpret_cast<float4*>(&As[lrow + 8][lc4]) = ra1;
    *reinterpret_cast<float4*>(&Bs[lrow][lc4]) = rb0;
    *reinterpret_cast<float4*>(&Bs[lrow + 8][lc4]) = rb1;
    __syncthreads();

    const int NC = K >> 4;
    for (int c = 0; c < NC; ++c) {
        if (c + 1 < NC) {               // issue next chunk's loads early
            const int kc = (c + 1) * 16;
            const int ma = m0 + lc4;
            ra0 = (ma < Mtot) ? *reinterpret_cast<const float4*>(&At[(size_t)(kc + lrow) * Mtot + ma])
                              : float4{0.f, 0.f, 0.f, 0.f};
            ra1 = (ma < Mtot) ? *reinterpret_cast<const float4*>(&At[(size_t)(kc + lrow + 8) * Mtot + ma])
                              : float4{0.f, 0.f, 0.f, 0.f};
            rb0 = *reinterpret_cast<const float4*>(&Bb[(size_t)(kc + lrow) * HWs + n0 + lc4]);
            rb1 = *reinterpret_cast<const float4*>(&Bb[(size_t)(kc + lrow + 8) * HWs + n0 + lc4]);
        }
#pragma unroll 4
        for (int k = 0; k < 16; ++k) {
            const float4 a0 = *reinterpret_cast<const float4*>(&As[k][mg * 4]);
            const float4 a1 = *reinterpret_cast<const float4*>(&As[k][64 + mg * 4]);
            const float4 b0 = *reinterpret_cast<const float4*>(&Bs[k][ng * 4]);
            const float4 b1 = *reinterpret_cast<const float4*>(&Bs[k][64 + ng * 4]);
            ROW8(0, a0.x) ROW8(1, a0.y) ROW8(2, a0.z) ROW8(3, a0.w)
            ROW8(4, a1.x) ROW8(5, a1.y) ROW8(6, a1.z) ROW8(7, a1.w)
        }
        if (c + 1 < NC) {
            __syncthreads();
            *reinterpret_cast<float4*>(&As[lrow][lc4]) = ra0;
            *reinterpret_cast<float4*>(&As[lrow + 8][lc4]) = ra1;
            *reinterpret_cast<float4*>(&Bs[lrow][lc4]) = rb0;
            *reinterpret_cast<float4*>(&Bs[lrow + 8][lc4]) = rb1;
            __syncthreads();
        }
    }

#pragma unroll
    for (int i = 0; i < 8; ++i) {
        const int m = m0 + ((i < 4) ? (mg * 4 + i) : (64 + mg * 4 + (i - 4)));
        if (m < Mtot) {
            const float bv = BIAS ? bias[m] : 0.f;
            float* crow = &Cb[(size_t)m * HWs + n0];
            float4 o0 = {acc[i][0] + bv, acc[i][1] + bv, acc[i][2] + bv, acc[i][3] + bv};
            float4 o1 = {acc[i][4] + bv, acc[i][5] + bv, acc[i][6] + bv, acc[i][7] + bv};
            *reinterpret_cast<float4*>(&crow[ng * 4]) = o0;
            *reinterpret_cast<float4*>(&crow[64 + ng * 4]) = o1;
        }
    }
}

// ---------------------------------------------------------------------------
// Involution: out[b, g*16+ci, p] = sum_kk wt[b, g*49+kk, p] * xpatch[ci, kk, p]
// ---------------------------------------------------------------------------
__global__ __launch_bounds__(256) void inv_k(
    const float* __restrict__ x, const float* __restrict__ wt,
    float* __restrict__ out)
{
    const int t = threadIdx.x;
    const int tile = blockIdx.x;       // 16 tiles (4x4 of 16x16)
    const int g = blockIdx.y;          // 16 groups
    const int b = blockIdx.z;          // 4 batches
    const int ty0 = (tile >> 2) * 16, tx0 = (tile & 3) * 16;

    __shared__ float xs[484 * 20];     // [spatial 22x22][16ch+4pad]

    const float* xb = x + (size_t)(b * 256 + g * 16) * HWs;
    for (int idx = t; idx < 484 * 16; idx += 256) {
        int ci = idx / 484;
        int sp = idx - ci * 484;
        int sy = sp / 22, sx = sp - sy * 22;
        int gy = ty0 + sy - 3, gx = tx0 + sx - 3;
        float v = 0.f;
        if ((unsigned)gy < 64u && (unsigned)gx < 64u)
            v = xb[(size_t)ci * HWs + gy * 64 + gx];
        xs[sp * 20 + ci] = v;
    }
    __syncthreads();

    const int py = t >> 4, px = t & 15;
    float acc[16];
#pragma unroll
    for (int i = 0; i < 16; ++i) acc[i] = 0.f;

    const float* wtb = wt + (size_t)(b * 16 + g) * 49 * HWs
                          + (ty0 + py) * 64 + tx0 + px;
    for (int dy = 0; dy < 7; ++dy) {
#pragma unroll
        for (int dx = 0; dx < 7; ++dx) {
            const int kk = dy * 7 + dx;
            const float wv = wtb[(size_t)kk * HWs];
            const float* xrow = &xs[((py + dy) * 22 + px + dx) * 20];
#pragma unroll
            for (int c4 = 0; c4 < 4; ++c4) {
                const float4 xv = *reinterpret_cast<const float4*>(&xrow[c4 * 4]);
                acc[c4 * 4 + 0] += wv * xv.x;
                acc[c4 * 4 + 1] += wv * xv.y;
                acc[c4 * 4 + 2] += wv * xv.z;
                acc[c4 * 4 + 3] += wv * xv.w;
            }
        }
    }

    float* ob = out + (size_t)(b * 256 + g * 16) * HWs + (ty0 + py) * 64 + tx0 + px;
#pragma unroll
    for (int ci = 0; ci < 16; ++ci)
        ob[(size_t)ci * HWs] = acc[ci];
}

// ---------------------------------------------------------------------------
extern "C" void kernel_launch(void* const* d_in, const int* in_sizes, int n_in,
                              void* d_out, int out_size, void* d_ws, size_t ws_size,
                              hipStream_t stream)
{
    const float* x     = (const float*)d_in[0];
    const float* w1    = (const float*)d_in[1];
    const float* gamma = (const float*)d_in[2];
    const float* beta  = (const float*)d_in[3];
    const float* mean  = (const float*)d_in[4];
    const float* var   = (const float*)d_in[5];
    const float* w2    = (const float*)d_in[6];
    const float* b2    = (const float*)d_in[7];
    const float* wp    = (const float*)d_in[8];
    float* out = (float*)d_out;
    float* ws  = (float*)d_ws;

    // workspace layout (floats)
    float* w1t = ws;                 // 16384
    float* b1  = ws + 16384;         // 64
    float* w2t = ws + 16448;         // 50176
    float* wpt = ws + 66624;         // 65536
    float* y   = ws + 132160;        // 4*64*4096   = 1,048,576
    float* wtb = ws + 1180736;       // 4*784*4096  = 12,845,056
    float* inv = ws + 14025792;      // 4*256*4096  = 4,194,304

    prep_k<<<517, 256, 0, stream>>>(w1, gamma, beta, mean, var, w2, wp,
                                    w1t, b1, w2t, wpt);
    // y = relu(BN(w1 @ x))
    gemm_k<true, true><<<dim3(256, 1), 256, 0, stream>>>(w1t, x, b1, y, 256, 64, 64);
    // wt = w2 @ y + b2   (M=784, K=64)
    gemm128_k<true><<<dim3(128, 7), 256, 0, stream>>>(w2t, y, b2, wtb, 64, 784);
    // involution
    inv_k<<<dim3(16, 16, 4), 256, 0, stream>>>(x, wtb, inv);
    // out = wp @ inv     (M=256, K=256)
    gemm128_k<false><<<dim3(128, 2), 256, 0, stream>>>(wpt, inv, nullptr, out, 256, 256);
}

// Round 4
// 108.639 us; speedup vs baseline: 2.6509x; 1.4451x over previous
//
#include <hip/hip_runtime.h>

typedef __attribute__((ext_vector_type(8))) short bf16x8;
typedef __attribute__((ext_vector_type(4))) float f32x4;
typedef unsigned short u16;

__device__ __forceinline__ float bf2f(u16 u) {
    unsigned int x = ((unsigned int)u) << 16;
    return __builtin_bit_cast(float, x);
}
__device__ __forceinline__ u16 f2bf(float f) {
    unsigned int x = __builtin_bit_cast(unsigned int, f);
    return (u16)((x + 0x7fffu + ((x >> 16) & 1u)) >> 16);
}

// ---------------------------------------------------------------------------
// Prep: w1t fp32 [k=256][m=64] (BN folded) + b1; w2pk bf16 [8][832][8] (pad);
// wppk bf16 [32][256][8].  B[k][m] = W[m][k] packed 8-k-contiguous per lane.
// ---------------------------------------------------------------------------
__global__ __launch_bounds__(256) void prep_k(
    const float* __restrict__ w1, const float* __restrict__ gamma,
    const float* __restrict__ beta, const float* __restrict__ mean,
    const float* __restrict__ var, const float* __restrict__ w2,
    const float* __restrict__ wp,
    float* __restrict__ w1t, float* __restrict__ b1,
    u16* __restrict__ w2pk, u16* __restrict__ wppk)
{
    int idx = blockIdx.x * 256 + threadIdx.x;
    if (idx < 16384) {                       // w1t[c][o] = w1[o][c]*scale[o]
        int c = idx >> 6, o = idx & 63;
        float s = gamma[o] * rsqrtf(var[o] + 1e-5f);
        w1t[idx] = w1[o * 256 + c] * s;
    } else if (idx < 16448) {                // b1
        int o = idx - 16384;
        float s = gamma[o] * rsqrtf(var[o] + 1e-5f);
        b1[o] = beta[o] - mean[o] * s;
    } else if (idx < 16448 + 53248) {        // w2pk[kg][m][j] = w2[m][kg*8+j]
        int i = idx - 16448;
        int kg = i / 6656, rem = i - kg * 6656;
        int m = rem >> 3, j = rem & 7;
        w2pk[i] = (m < 784) ? f2bf(w2[m * 64 + kg * 8 + j]) : (u16)0;
    } else if (idx < 16448 + 53248 + 65536) { // wppk[kg][m][j] = wp[m][kg*8+j]
        int i = idx - 16448 - 53248;
        int kg = i >> 11, m = (i >> 3) & 255, j = i & 7;
        wppk[i] = f2bf(wp[m * 256 + kg * 8 + j]);
    }
}

// ---------------------------------------------------------------------------
// Stage 1: y = relu(BN(w1 @ x)), fp32 vector GEMM (K=256, M=64), output
// written k-packed bf16: ypk[b][kg=8][4096][8].
// ---------------------------------------------------------------------------
__global__ __launch_bounds__(256) void gemm1_k(
    const float* __restrict__ At,   // w1t [256][64]
    const float* __restrict__ x,    // [4][256][4096]
    const float* __restrict__ b1,
    u16* __restrict__ ypk)
{
    const int t = threadIdx.x;
    const int batch = blockIdx.x >> 6;
    const int n0 = (blockIdx.x & 63) * 64;
    const float* Bb = x + (size_t)batch * 256 * 4096;

    __shared__ float As[64][64];
    __shared__ float Bs[64][64];

    const int og = t >> 4, pg = t & 15;
    float acc[4][4];
#pragma unroll
    for (int i = 0; i < 4; ++i)
#pragma unroll
        for (int j = 0; j < 4; ++j) acc[i][j] = 0.f;

    for (int kc = 0; kc < 256; kc += 64) {
#pragma unroll
        for (int r = 0; r < 16; ++r) {
            int idx = t + r * 256;
            int kk = idx >> 6, col = idx & 63;
            As[kk][col] = At[(size_t)(kc + kk) * 64 + col];
            Bs[kk][col] = Bb[(size_t)(kc + kk) * 4096 + n0 + col];
        }
        __syncthreads();
#pragma unroll 8
        for (int k = 0; k < 64; ++k) {
            const float4 av = *reinterpret_cast<const float4*>(&As[k][og * 4]);
            const float4 bv = *reinterpret_cast<const float4*>(&Bs[k][pg * 4]);
            acc[0][0] += av.x * bv.x; acc[0][1] += av.x * bv.y;
            acc[0][2] += av.x * bv.z; acc[0][3] += av.x * bv.w;
            acc[1][0] += av.y * bv.x; acc[1][1] += av.y * bv.y;
            acc[1][2] += av.y * bv.z; acc[1][3] += av.y * bv.w;
            acc[2][0] += av.z * bv.x; acc[2][1] += av.z * bv.y;
            acc[2][2] += av.z * bv.z; acc[2][3] += av.z * bv.w;
            acc[3][0] += av.w * bv.x; acc[3][1] += av.w * bv.y;
            acc[3][2] += av.w * bv.z; acc[3][3] += av.w * bv.w;
        }
        __syncthreads();
    }

    const int kg = og >> 1, joff = (og & 1) * 4;
    float bb[4];
#pragma unroll
    for (int i = 0; i < 4; ++i) bb[i] = b1[og * 4 + i];
#pragma unroll
    for (int jj = 0; jj < 4; ++jj) {
        u16 p[4];
#pragma unroll
        for (int i = 0; i < 4; ++i)
            p[i] = f2bf(fmaxf(acc[i][jj] + bb[i], 0.f));
        uint2 v;
        v.x = (unsigned)p[0] | ((unsigned)p[1] << 16);
        v.y = (unsigned)p[2] | ((unsigned)p[3] << 16);
        *reinterpret_cast<uint2*>(
            &ypk[(((size_t)batch * 8 + kg) * 4096 + n0 + pg * 4 + jj) * 8 + joff]) = v;
    }
}

// ---------------------------------------------------------------------------
// MFMA GEMM: D[n][m] = sum_k A[n][k] * W[k][m]  (swapped orientation).
// A (activations) k-packed [K/8][4096][8] per batch, streamed 128n x 64k,
// double-buffered, XOR-swizzled LDS. W (weights) k-packed [K/8][MP][8],
// staged fully. Block = 64m x 128n, 4 waves of 32m x 64n.
// ---------------------------------------------------------------------------
template<int K, int MP, bool OUT_BF16>
__global__ __launch_bounds__(256) void mgemm_k(
    const u16* __restrict__ Apk,
    const u16* __restrict__ Wpk,
    const float* __restrict__ bias,
    void* __restrict__ Cout,
    int Mout)
{
    constexpr int NK = K / 64;
    constexpr int DB = (NK > 1) ? 2 : 1;
    __shared__ u16 As[DB][8 * 128 * 8];
    __shared__ u16 Ws[(K / 8) * 64 * 8];

    const int t = threadIdx.x;
    const int lane = t & 63, wave = t >> 6;
    const int m0 = blockIdx.x * 64;
    const int batch = blockIdx.y >> 5;
    const int n0 = (blockIdx.y & 31) * 128;
    const u16* Ab = Apk + (size_t)batch * (K / 8) * 4096 * 8;

    const int n0w = (wave & 1) * 64;
    const int m0w = (wave >> 1) * 32;
    const int ln = lane & 15, lk = lane >> 4;

    // stage weights (whole K x 64m slice), m XOR-swizzled by kg
    for (int s = t; s < (K / 8) * 64; s += 256) {
        int kg = s >> 6, m = s & 63;
        const uint4 v = *reinterpret_cast<const uint4*>(
            &Wpk[((size_t)kg * MP + m0 + m) * 8]);
        *reinterpret_cast<uint4*>(&Ws[((size_t)kg * 64 + (m ^ (kg & 7))) * 8]) = v;
    }

    // stage activations step 0
    uint4 rs[4];
#pragma unroll
    for (int r = 0; r < 4; ++r) {
        int s = r * 256 + t, kg = s >> 7, nn = s & 127;
        rs[r] = *reinterpret_cast<const uint4*>(&Ab[((size_t)kg * 4096 + n0 + nn) * 8]);
    }
#pragma unroll
    for (int r = 0; r < 4; ++r) {
        int s = r * 256 + t, kg = s >> 7, nn = s & 127;
        *reinterpret_cast<uint4*>(&As[0][((size_t)kg * 128 + (nn ^ kg)) * 8]) = rs[r];
    }
    __syncthreads();

    f32x4 acc[4][2];
#pragma unroll
    for (int i = 0; i < 4; ++i)
#pragma unroll
        for (int f = 0; f < 2; ++f)
#pragma unroll
            for (int e = 0; e < 4; ++e) acc[i][f][e] = 0.f;

    for (int ks = 0; ks < NK; ++ks) {
        const int cur = ks & (DB - 1);
        if (ks + 1 < NK) {      // issue next-step global loads early
#pragma unroll
            for (int r = 0; r < 4; ++r) {
                int s = r * 256 + t, kg = s >> 7, nn = s & 127;
                rs[r] = *reinterpret_cast<const uint4*>(
                    &Ab[(((size_t)(ks + 1) * 8 + kg) * 4096 + n0 + nn) * 8]);
            }
        }
#pragma unroll
        for (int k32 = 0; k32 < 2; ++k32) {
            const int kg = k32 * 4 + lk;
            bf16x8 a[4], b[2];
#pragma unroll
            for (int i = 0; i < 4; ++i) {
                int n = n0w + i * 16 + ln;
                a[i] = *reinterpret_cast<const bf16x8*>(
                    &As[cur][((size_t)kg * 128 + (n ^ kg)) * 8]);
            }
            const int kgw = ks * 8 + kg;
#pragma unroll
            for (int f = 0; f < 2; ++f) {
                int m = m0w + f * 16 + ln;
                b[f] = *reinterpret_cast<const bf16x8*>(
                    &Ws[((size_t)kgw * 64 + (m ^ (kgw & 7))) * 8]);
            }
#pragma unroll
            for (int i = 0; i < 4; ++i)
#pragma unroll
                for (int f = 0; f < 2; ++f)
                    acc[i][f] = __builtin_amdgcn_mfma_f32_16x16x32_bf16(
                        a[i], b[f], acc[i][f], 0, 0, 0);
        }
        if (ks + 1 < NK) {      // write next buffer (prev readers passed barrier)
#pragma unroll
            for (int r = 0; r < 4; ++r) {
                int s = r * 256 + t, kg = s >> 7, nn = s & 127;
                *reinterpret_cast<uint4*>(
                    &As[cur ^ 1][((size_t)kg * 128 + (nn ^ kg)) * 8]) = rs[r];
            }
            __syncthreads();
        }
    }

    // epilogue: lane holds rows n = (lane>>4)*4 + r, col m = lane&15
#pragma unroll
    for (int f = 0; f < 2; ++f) {
        const int m = m0 + m0w + f * 16 + ln;
        if (m < Mout) {
#pragma unroll
            for (int i = 0; i < 4; ++i) {
                const int n = n0 + n0w + i * 16 + lk * 4;
                const size_t off = ((size_t)batch * Mout + m) * 4096 + n;
                if (OUT_BF16) {
                    const float bv = bias[m];
                    u16 p[4];
#pragma unroll
                    for (int r = 0; r < 4; ++r) p[r] = f2bf(acc[i][f][r] + bv);
                    uint2 v;
                    v.x = (unsigned)p[0] | ((unsigned)p[1] << 16);
                    v.y = (unsigned)p[2] | ((unsigned)p[3] << 16);
                    *reinterpret_cast<uint2*>(&((u16*)Cout)[off]) = v;
                } else {
                    float4 v = {acc[i][f][0], acc[i][f][1], acc[i][f][2], acc[i][f][3]};
                    *reinterpret_cast<float4*>(&((float*)Cout)[off]) = v;
                }
            }
        }
    }
}

// ---------------------------------------------------------------------------
// Involution: reads wt (bf16), x (fp32, LDS-staged); writes inv k-packed bf16
// invpk[b][kg=32][4096][8].
// ---------------------------------------------------------------------------
__global__ __launch_bounds__(256) void inv_k(
    const float* __restrict__ x, const u16* __restrict__ wt,
    u16* __restrict__ invpk)
{
    const int t = threadIdx.x;
    const int tile = blockIdx.x;
    const int g = blockIdx.y;
    const int b = blockIdx.z;
    const int ty0 = (tile >> 2) * 16, tx0 = (tile & 3) * 16;

    __shared__ float xs[484 * 20];

    const float* xb = x + (size_t)(b * 256 + g * 16) * 4096;
    for (int idx = t; idx < 484 * 16; idx += 256) {
        int ci = idx / 484;
        int sp = idx - ci * 484;
        int sy = sp / 22, sx = sp - sy * 22;
        int gy = ty0 + sy - 3, gx = tx0 + sx - 3;
        float v = 0.f;
        if ((unsigned)gy < 64u && (unsigned)gx < 64u)
            v = xb[(size_t)ci * 4096 + gy * 64 + gx];
        xs[sp * 20 + ci] = v;
    }
    __syncthreads();

    const int py = t >> 4, px = t & 15;
    const int pix = (ty0 + py) * 64 + tx0 + px;
    float acc[16];
#pragma unroll
    for (int i = 0; i < 16; ++i) acc[i] = 0.f;

    const u16* wtb = wt + ((size_t)b * 784 + g * 49) * 4096 + pix;
    for (int dy = 0; dy < 7; ++dy) {
#pragma unroll
        for (int dx = 0; dx < 7; ++dx) {
            const int kk = dy * 7 + dx;
            const float wv = bf2f(wtb[(size_t)kk * 4096]);
            const float* xrow = &xs[((py + dy) * 22 + px + dx) * 20];
#pragma unroll
            for (int c4 = 0; c4 < 4; ++c4) {
                const float4 xv = *reinterpret_cast<const float4*>(&xrow[c4 * 4]);
                acc[c4 * 4 + 0] += wv * xv.x;
                acc[c4 * 4 + 1] += wv * xv.y;
                acc[c4 * 4 + 2] += wv * xv.z;
                acc[c4 * 4 + 3] += wv * xv.w;
            }
        }
    }

#pragma unroll
    for (int h = 0; h < 2; ++h) {
        u16 p[8];
#pragma unroll
        for (int j = 0; j < 8; ++j) p[j] = f2bf(acc[h * 8 + j]);
        uint4 v;
        v.x = (unsigned)p[0] | ((unsigned)p[1] << 16);
        v.y = (unsigned)p[2] | ((unsigned)p[3] << 16);
        v.z = (unsigned)p[4] | ((unsigned)p[5] << 16);
        v.w = (unsigned)p[6] | ((unsigned)p[7] << 16);
        *reinterpret_cast<uint4*>(
            &invpk[(((size_t)b * 32 + g * 2 + h) * 4096 + pix) * 8]) = v;
    }
}

// ---------------------------------------------------------------------------
extern "C" void kernel_launch(void* const* d_in, const int* in_sizes, int n_in,
                              void* d_out, int out_size, void* d_ws, size_t ws_size,
                              hipStream_t stream)
{
    const float* x     = (const float*)d_in[0];
    const float* w1    = (const float*)d_in[1];
    const float* gamma = (const float*)d_in[2];
    const float* beta  = (const float*)d_in[3];
    const float* mean  = (const float*)d_in[4];
    const float* var   = (const float*)d_in[5];
    const float* w2    = (const float*)d_in[6];
    const float* b2    = (const float*)d_in[7];
    const float* wp    = (const float*)d_in[8];
    float* out = (float*)d_out;
    float* ws  = (float*)d_ws;

    // fp32 region
    float* w1t = ws;               // 16384
    float* b1  = ws + 16384;       // 64
    // bf16 region (16B-aligned: 16448 floats = 65792 B)
    u16* u = (u16*)(ws + 16448);
    u16* w2pk  = u;                // 8*832*8    = 53248
    u16* wppk  = u + 53248;        // 32*256*8   = 65536
    u16* ypk   = u + 118784;       // 4*8*4096*8 = 1048576
    u16* wtb   = u + 1167360;      // 4*784*4096 = 12845056
    u16* invpk = u + 14012416;     // 4*32*4096*8= 4194304
                                   // total ~36.5 MB

    prep_k<<<529, 256, 0, stream>>>(w1, gamma, beta, mean, var, w2, wp,
                                    w1t, b1, w2pk, wppk);
    // y = relu(BN(w1 @ x)) -> k-packed bf16
    gemm1_k<<<256, 256, 0, stream>>>(w1t, x, b1, ypk);
    // wt = w2 @ y + b2  (K=64, M=784 pad 832) -> bf16 [b][784][4096]
    mgemm_k<64, 832, true><<<dim3(13, 128), 256, 0, stream>>>(
        ypk, w2pk, b2, (void*)wtb, 784);
    // involution -> k-packed bf16
    inv_k<<<dim3(16, 16, 4), 256, 0, stream>>>(x, wtb, invpk);
    // out = wp @ inv  (K=256, M=256) -> fp32
    mgemm_k<256, 256, false><<<dim3(4, 128), 256, 0, stream>>>(
        invpk, wppk, nullptr, (void*)out, 256);
}

// Round 5
// 76.982 us; speedup vs baseline: 3.7410x; 1.4112x over previous
//
#include <hip/hip_runtime.h>

typedef __attribute__((ext_vector_type(8))) short bf16x8;
typedef __attribute__((ext_vector_type(4))) float f32x4;
typedef unsigned short u16;

__device__ __forceinline__ float bf2f(u16 u) {
    unsigned int x = ((unsigned int)u) << 16;
    return __builtin_bit_cast(float, x);
}
__device__ __forceinline__ u16 f2bf(float f) {
    unsigned int x = __builtin_bit_cast(unsigned int, f);
    return (u16)((x + 0x7fffu + ((x >> 16) & 1u)) >> 16);
}

// ---------------------------------------------------------------------------
// Prep: w1pk bf16 [32][64][8] (BN folded into weights), b1 fp32[64],
// w2pk bf16 [8][832][8] (pad 784->832), wppk bf16 [32][256][8].
// ---------------------------------------------------------------------------
__global__ __launch_bounds__(256) void prep_k(
    const float* __restrict__ w1, const float* __restrict__ gamma,
    const float* __restrict__ beta, const float* __restrict__ mean,
    const float* __restrict__ var, const float* __restrict__ w2,
    const float* __restrict__ wp,
    u16* __restrict__ w1pk, float* __restrict__ b1,
    u16* __restrict__ w2pk, u16* __restrict__ wppk)
{
    int idx = blockIdx.x * 256 + threadIdx.x;
    if (idx < 16384) {                        // w1pk[kg][m][j] = w1[m][kg*8+j]*s[m]
        int kg = idx >> 9, m = (idx >> 3) & 63, j = idx & 7;
        float s = gamma[m] * rsqrtf(var[m] + 1e-5f);
        w1pk[idx] = f2bf(w1[m * 256 + kg * 8 + j] * s);
    } else if (idx < 16448) {                 // b1
        int o = idx - 16384;
        float s = gamma[o] * rsqrtf(var[o] + 1e-5f);
        b1[o] = beta[o] - mean[o] * s;
    } else if (idx < 16448 + 53248) {         // w2pk[kg][m][j] = w2[m][kg*8+j]
        int i = idx - 16448;
        int kg = i / 6656, rem = i - kg * 6656;
        int m = rem >> 3, j = rem & 7;
        w2pk[i] = (m < 784) ? f2bf(w2[m * 64 + kg * 8 + j]) : (u16)0;
    } else if (idx < 16448 + 53248 + 65536) { // wppk[kg][m][j] = wp[m][kg*8+j]
        int i = idx - 16448 - 53248;
        int kg = i >> 11, m = (i >> 3) & 255, j = i & 7;
        wppk[i] = f2bf(wp[m * 256 + kg * 8 + j]);
    }
}

// ---------------------------------------------------------------------------
// xpack: x fp32 [b][256][4096] -> xpk bf16 k-packed [b][32][4096][8]
// ---------------------------------------------------------------------------
__global__ __launch_bounds__(256) void xpack_k(
    const float* __restrict__ x, u16* __restrict__ xpk)
{
    const int t = threadIdx.x;
    const int kg = blockIdx.y, b = blockIdx.z;
    const int pix = blockIdx.x * 256 + t;
    const float* xb = x + ((size_t)(b * 256 + kg * 8)) * 4096 + pix;
    u16 p[8];
#pragma unroll
    for (int j = 0; j < 8; ++j) p[j] = f2bf(xb[(size_t)j * 4096]);
    uint4 v;
    v.x = (unsigned)p[0] | ((unsigned)p[1] << 16);
    v.y = (unsigned)p[2] | ((unsigned)p[3] << 16);
    v.z = (unsigned)p[4] | ((unsigned)p[5] << 16);
    v.w = (unsigned)p[6] | ((unsigned)p[7] << 16);
    *reinterpret_cast<uint4*>(&xpk[(((size_t)b * 32 + kg) * 4096 + pix) * 8]) = v;
}

// ---------------------------------------------------------------------------
// Stage 1 MFMA GEMM: y[n][m] = relu(sum_k x[n][k]*W1[k][m] + b1[m]).
// K=256, M=64, 64n per block, 4 waves each 16m x 64n. Output k-packed bf16.
// ---------------------------------------------------------------------------
__global__ __launch_bounds__(256) void gemm1m_k(
    const u16* __restrict__ xpk, const u16* __restrict__ w1pk,
    const float* __restrict__ b1, u16* __restrict__ ypk)
{
    __shared__ u16 Ws[32 * 64 * 8];    // 32 KB, full K x 64m
    __shared__ u16 As[2][8 * 64 * 8];  // 2 x 8 KB

    const int t = threadIdx.x, lane = t & 63, wave = t >> 6;
    const int b = blockIdx.y, n0 = blockIdx.x * 64;
    const int ln = lane & 15, lk = lane >> 4;
    const u16* Ab = xpk + (size_t)b * 32 * 4096 * 8;

    // stage full weights (m XOR-swizzled by kg&7)
    for (int s = t; s < 2048; s += 256) {
        int kg = s >> 6, m = s & 63;
        uint4 v = *reinterpret_cast<const uint4*>(&w1pk[(size_t)s * 8]);
        *reinterpret_cast<uint4*>(&Ws[((kg * 64) + (m ^ (kg & 7))) * 8]) = v;
    }
    // stage activations step 0
    uint4 rs[2];
#pragma unroll
    for (int r = 0; r < 2; ++r) {
        int s = r * 256 + t, kg = s >> 6, nn = s & 63;
        rs[r] = *reinterpret_cast<const uint4*>(&Ab[((size_t)kg * 4096 + n0 + nn) * 8]);
    }
#pragma unroll
    for (int r = 0; r < 2; ++r) {
        int s = r * 256 + t, kg = s >> 6, nn = s & 63;
        *reinterpret_cast<uint4*>(&As[0][((kg * 64) + (nn ^ kg)) * 8]) = rs[r];
    }
    __syncthreads();

    f32x4 acc[4];
#pragma unroll
    for (int i = 0; i < 4; ++i)
#pragma unroll
        for (int e = 0; e < 4; ++e) acc[i][e] = 0.f;

    for (int ks = 0; ks < 4; ++ks) {
        const int cur = ks & 1;
        if (ks < 3) {
#pragma unroll
            for (int r = 0; r < 2; ++r) {
                int s = r * 256 + t, kg = s >> 6, nn = s & 63;
                rs[r] = *reinterpret_cast<const uint4*>(
                    &Ab[(((size_t)(ks + 1) * 8 + kg) * 4096 + n0 + nn) * 8]);
            }
        }
#pragma unroll
        for (int k32 = 0; k32 < 2; ++k32) {
            const int kgl = k32 * 4 + lk;
            const int kgw = ks * 8 + kgl;
            bf16x8 a[4];
#pragma unroll
            for (int i = 0; i < 4; ++i) {
                int n = i * 16 + ln;
                a[i] = *reinterpret_cast<const bf16x8*>(
                    &As[cur][((kgl * 64) + (n ^ kgl)) * 8]);
            }
            const int m = wave * 16 + ln;
            const bf16x8 bfr = *reinterpret_cast<const bf16x8*>(
                &Ws[((kgw * 64) + (m ^ (kgw & 7))) * 8]);
#pragma unroll
            for (int i = 0; i < 4; ++i)
                acc[i] = __builtin_amdgcn_mfma_f32_16x16x32_bf16(a[i], bfr, acc[i], 0, 0, 0);
        }
        if (ks < 3) {
#pragma unroll
            for (int r = 0; r < 2; ++r) {
                int s = r * 256 + t, kg = s >> 6, nn = s & 63;
                *reinterpret_cast<uint4*>(
                    &As[cur ^ 1][((kg * 64) + (nn ^ kg)) * 8]) = rs[r];
            }
            __syncthreads();
        }
    }

    // epilogue: m = wave*16+ln, rows n = n0 + i*16 + lk*4 + r; relu+bias,
    // write k-packed ypk[b][m>>3][n][m&7]
    const int m = wave * 16 + ln;
    const float bv = b1[m];
    u16* yb = ypk + ((size_t)b * 8 + (m >> 3)) * 4096 * 8 + (m & 7);
#pragma unroll
    for (int i = 0; i < 4; ++i) {
        const int n = n0 + i * 16 + lk * 4;
#pragma unroll
        for (int r = 0; r < 4; ++r)
            yb[(size_t)(n + r) * 8] = f2bf(fmaxf(acc[i][r] + bv, 0.f));
    }
}

// ---------------------------------------------------------------------------
// MFMA GEMM: D[n][m] = sum_k A[n][k] * W[k][m].  A k-packed [K/8][4096][8]
// per batch, W k-packed [K/8][MP][8]. Block 64m x 128n, 4 waves 32m x 64n.
// ---------------------------------------------------------------------------
template<int K, int MP, bool OUT_BF16>
__global__ __launch_bounds__(256) void mgemm_k(
    const u16* __restrict__ Apk,
    const u16* __restrict__ Wpk,
    const float* __restrict__ bias,
    void* __restrict__ Cout,
    int Mout)
{
    constexpr int NK = K / 64;
    constexpr int DB = (NK > 1) ? 2 : 1;
    __shared__ u16 As[DB][8 * 128 * 8];
    __shared__ u16 Ws[(K / 8) * 64 * 8];

    const int t = threadIdx.x;
    const int lane = t & 63, wave = t >> 6;
    const int m0 = blockIdx.x * 64;
    const int batch = blockIdx.y >> 5;
    const int n0 = (blockIdx.y & 31) * 128;
    const u16* Ab = Apk + (size_t)batch * (K / 8) * 4096 * 8;

    const int n0w = (wave & 1) * 64;
    const int m0w = (wave >> 1) * 32;
    const int ln = lane & 15, lk = lane >> 4;

    for (int s = t; s < (K / 8) * 64; s += 256) {
        int kg = s >> 6, m = s & 63;
        const uint4 v = *reinterpret_cast<const uint4*>(
            &Wpk[((size_t)kg * MP + m0 + m) * 8]);
        *reinterpret_cast<uint4*>(&Ws[((size_t)kg * 64 + (m ^ (kg & 7))) * 8]) = v;
    }

    uint4 rs[4];
#pragma unroll
    for (int r = 0; r < 4; ++r) {
        int s = r * 256 + t, kg = s >> 7, nn = s & 127;
        rs[r] = *reinterpret_cast<const uint4*>(&Ab[((size_t)kg * 4096 + n0 + nn) * 8]);
    }
#pragma unroll
    for (int r = 0; r < 4; ++r) {
        int s = r * 256 + t, kg = s >> 7, nn = s & 127;
        *reinterpret_cast<uint4*>(&As[0][((size_t)kg * 128 + (nn ^ kg)) * 8]) = rs[r];
    }
    __syncthreads();

    f32x4 acc[4][2];
#pragma unroll
    for (int i = 0; i < 4; ++i)
#pragma unroll
        for (int f = 0; f < 2; ++f)
#pragma unroll
            for (int e = 0; e < 4; ++e) acc[i][f][e] = 0.f;

    for (int ks = 0; ks < NK; ++ks) {
        const int cur = ks & (DB - 1);
        if (ks + 1 < NK) {
#pragma unroll
            for (int r = 0; r < 4; ++r) {
                int s = r * 256 + t, kg = s >> 7, nn = s & 127;
                rs[r] = *reinterpret_cast<const uint4*>(
                    &Ab[(((size_t)(ks + 1) * 8 + kg) * 4096 + n0 + nn) * 8]);
            }
        }
#pragma unroll
        for (int k32 = 0; k32 < 2; ++k32) {
            const int kg = k32 * 4 + lk;
            bf16x8 a[4], b[2];
#pragma unroll
            for (int i = 0; i < 4; ++i) {
                int n = n0w + i * 16 + ln;
                a[i] = *reinterpret_cast<const bf16x8*>(
                    &As[cur][((size_t)kg * 128 + (n ^ kg)) * 8]);
            }
            const int kgw = ks * 8 + kg;
#pragma unroll
            for (int f = 0; f < 2; ++f) {
                int m = m0w + f * 16 + ln;
                b[f] = *reinterpret_cast<const bf16x8*>(
                    &Ws[((size_t)kgw * 64 + (m ^ (kgw & 7))) * 8]);
            }
#pragma unroll
            for (int i = 0; i < 4; ++i)
#pragma unroll
                for (int f = 0; f < 2; ++f)
                    acc[i][f] = __builtin_amdgcn_mfma_f32_16x16x32_bf16(
                        a[i], b[f], acc[i][f], 0, 0, 0);
        }
        if (ks + 1 < NK) {
#pragma unroll
            for (int r = 0; r < 4; ++r) {
                int s = r * 256 + t, kg = s >> 7, nn = s & 127;
                *reinterpret_cast<uint4*>(
                    &As[cur ^ 1][((size_t)kg * 128 + (nn ^ kg)) * 8]) = rs[r];
            }
            __syncthreads();
        }
    }

#pragma unroll
    for (int f = 0; f < 2; ++f) {
        const int m = m0 + m0w + f * 16 + ln;
        if (m < Mout) {
#pragma unroll
            for (int i = 0; i < 4; ++i) {
                const int n = n0 + n0w + i * 16 + lk * 4;
                const size_t off = ((size_t)batch * Mout + m) * 4096 + n;
                if (OUT_BF16) {
                    const float bv = bias[m];
                    u16 p[4];
#pragma unroll
                    for (int r = 0; r < 4; ++r) p[r] = f2bf(acc[i][f][r] + bv);
                    uint2 v;
                    v.x = (unsigned)p[0] | ((unsigned)p[1] << 16);
                    v.y = (unsigned)p[2] | ((unsigned)p[3] << 16);
                    *reinterpret_cast<uint2*>(&((u16*)Cout)[off]) = v;
                } else {
                    float4 v = {acc[i][f][0], acc[i][f][1], acc[i][f][2], acc[i][f][3]};
                    *reinterpret_cast<float4*>(&((float*)Cout)[off]) = v;
                }
            }
        }
    }
}

// ---------------------------------------------------------------------------
// Involution: reads wt (bf16), x (fp32, LDS-staged); writes inv k-packed bf16
// ---------------------------------------------------------------------------
__global__ __launch_bounds__(256) void inv_k(
    const float* __restrict__ x, const u16* __restrict__ wt,
    u16* __restrict__ invpk)
{
    const int t = threadIdx.x;
    const int tile = blockIdx.x;
    const int g = blockIdx.y;
    const int b = blockIdx.z;
    const int ty0 = (tile >> 2) * 16, tx0 = (tile & 3) * 16;

    __shared__ float xs[484 * 20];

    const float* xb = x + (size_t)(b * 256 + g * 16) * 4096;
    for (int idx = t; idx < 484 * 16; idx += 256) {
        int ci = idx / 484;
        int sp = idx - ci * 484;
        int sy = sp / 22, sx = sp - sy * 22;
        int gy = ty0 + sy - 3, gx = tx0 + sx - 3;
        float v = 0.f;
        if ((unsigned)gy < 64u && (unsigned)gx < 64u)
            v = xb[(size_t)ci * 4096 + gy * 64 + gx];
        xs[sp * 20 + ci] = v;
    }
    __syncthreads();

    const int py = t >> 4, px = t & 15;
    const int pix = (ty0 + py) * 64 + tx0 + px;
    float acc[16];
#pragma unroll
    for (int i = 0; i < 16; ++i) acc[i] = 0.f;

    const u16* wtb = wt + ((size_t)b * 784 + g * 49) * 4096 + pix;
    for (int dy = 0; dy < 7; ++dy) {
#pragma unroll
        for (int dx = 0; dx < 7; ++dx) {
            const int kk = dy * 7 + dx;
            const float wv = bf2f(wtb[(size_t)kk * 4096]);
            const float* xrow = &xs[((py + dy) * 22 + px + dx) * 20];
#pragma unroll
            for (int c4 = 0; c4 < 4; ++c4) {
                const float4 xv = *reinterpret_cast<const float4*>(&xrow[c4 * 4]);
                acc[c4 * 4 + 0] += wv * xv.x;
                acc[c4 * 4 + 1] += wv * xv.y;
                acc[c4 * 4 + 2] += wv * xv.z;
                acc[c4 * 4 + 3] += wv * xv.w;
            }
        }
    }

#pragma unroll
    for (int h = 0; h < 2; ++h) {
        u16 p[8];
#pragma unroll
        for (int j = 0; j < 8; ++j) p[j] = f2bf(acc[h * 8 + j]);
        uint4 v;
        v.x = (unsigned)p[0] | ((unsigned)p[1] << 16);
        v.y = (unsigned)p[2] | ((unsigned)p[3] << 16);
        v.z = (unsigned)p[4] | ((unsigned)p[5] << 16);
        v.w = (unsigned)p[6] | ((unsigned)p[7] << 16);
        *reinterpret_cast<uint4*>(
            &invpk[(((size_t)b * 32 + g * 2 + h) * 4096 + pix) * 8]) = v;
    }
}

// ---------------------------------------------------------------------------
extern "C" void kernel_launch(void* const* d_in, const int* in_sizes, int n_in,
                              void* d_out, int out_size, void* d_ws, size_t ws_size,
                              hipStream_t stream)
{
    const float* x     = (const float*)d_in[0];
    const float* w1    = (const float*)d_in[1];
    const float* gamma = (const float*)d_in[2];
    const float* beta  = (const float*)d_in[3];
    const float* mean  = (const float*)d_in[4];
    const float* var   = (const float*)d_in[5];
    const float* w2    = (const float*)d_in[6];
    const float* b2    = (const float*)d_in[7];
    const float* wp    = (const float*)d_in[8];
    float* out = (float*)d_out;
    float* ws  = (float*)d_ws;

    float* b1 = ws;                 // 64 floats
    u16* u = (u16*)(ws + 64);
    u16* w1pk  = u;                 // 16384
    u16* w2pk  = u + 16384;         // 53248
    u16* wppk  = u + 69632;         // 65536
    u16* xpk   = u + 135168;        // 4*32*4096*8 = 4194304
    u16* ypk   = u + 4329472;       // 4*8*4096*8  = 1048576
    u16* wtb   = u + 5378048;       // 4*784*4096  = 12845056
    u16* invpk = u + 18223104;      // 4*32*4096*8 = 4194304
                                    // total ~44.8 MB

    prep_k<<<529, 256, 0, stream>>>(w1, gamma, beta, mean, var, w2, wp,
                                    w1pk, b1, w2pk, wppk);
    xpack_k<<<dim3(16, 32, 4), 256, 0, stream>>>(x, xpk);
    // y = relu(BN(w1 @ x)) -> k-packed bf16
    gemm1m_k<<<dim3(64, 4), 256, 0, stream>>>(xpk, w1pk, b1, ypk);
    // wt = w2 @ y + b2  (K=64, M=784 pad 832) -> bf16 [b][784][4096]
    mgemm_k<64, 832, true><<<dim3(13, 128), 256, 0, stream>>>(
        ypk, w2pk, b2, (void*)wtb, 784);
    // involution -> k-packed bf16
    inv_k<<<dim3(16, 16, 4), 256, 0, stream>>>(x, wtb, invpk);
    // out = wp @ inv  (K=256, M=256) -> fp32
    mgemm_k<256, 256, false><<<dim3(4, 128), 256, 0, stream>>>(
        invpk, wppk, nullptr, (void*)out, 256);
}

// Round 6
// 49.539 us; speedup vs baseline: 5.8133x; 1.5540x over previous
//
#include <hip/hip_runtime.h>

typedef __attribute__((ext_vector_type(8))) short bf16x8;
typedef __attribute__((ext_vector_type(4))) float f32x4;
typedef __attribute__((ext_vector_type(8))) _Float16 h16x8;
typedef unsigned short u16;
typedef unsigned int u32;

__device__ __forceinline__ float bf2f(u16 u) {
    u32 x = ((u32)u) << 16;
    return __builtin_bit_cast(float, x);
}
__device__ __forceinline__ u16 f2bf(float f) {
    u32 x = __builtin_bit_cast(u32, f);
    return (u16)((x + 0x7fffu + ((x >> 16) & 1u)) >> 16);
}
__device__ __forceinline__ u16 f2h(float f) {
    _Float16 h = (_Float16)f;
    return __builtin_bit_cast(u16, h);
}
__device__ __forceinline__ u32 bfpair_to_h2(u32 a) {
    float f0 = bf2f((u16)(a & 0xffffu));
    float f1 = bf2f((u16)(a >> 16));
    return (u32)f2h(f0) | ((u32)f2h(f1) << 16);
}

// ---------------------------------------------------------------------------
// prep2: xpack (x fp32 -> xpk bf16 k-packed [b][32][4096][8]) + weight prep:
// w1pk bf16 [32][64][8] (BN folded), b1 fp32[64],
// w2gpk bf16 [g=16][kg=8][m=64][8] (m=kk, pad 49->64), wppk bf16 [32][256][8].
// ---------------------------------------------------------------------------
__global__ __launch_bounds__(256) void prep2_k(
    const float* __restrict__ x,
    const float* __restrict__ w1, const float* __restrict__ gamma,
    const float* __restrict__ beta, const float* __restrict__ mean,
    const float* __restrict__ var, const float* __restrict__ w2,
    const float* __restrict__ wp,
    u16* __restrict__ xpk, u16* __restrict__ w1pk, float* __restrict__ b1,
    u16* __restrict__ w2gpk, u16* __restrict__ wppk)
{
    const int t = threadIdx.x;
    const int blk = blockIdx.x;
    if (blk < 2048) {                    // xpack
        const int b = blk >> 9, kg = (blk >> 4) & 31, pb = blk & 15;
        const int pix = pb * 256 + t;
        const float* xb = x + ((size_t)(b * 256 + kg * 8)) * 4096 + pix;
        u16 p[8];
#pragma unroll
        for (int j = 0; j < 8; ++j) p[j] = f2bf(xb[(size_t)j * 4096]);
        uint4 v;
        v.x = (u32)p[0] | ((u32)p[1] << 16);
        v.y = (u32)p[2] | ((u32)p[3] << 16);
        v.z = (u32)p[4] | ((u32)p[5] << 16);
        v.w = (u32)p[6] | ((u32)p[7] << 16);
        *reinterpret_cast<uint4*>(&xpk[(((size_t)b * 32 + kg) * 4096 + pix) * 8]) = v;
        return;
    }
    int idx = (blk - 2048) * 256 + t;
    if (idx < 16384) {                   // w1pk[kg][m][j] = w1[m][kg*8+j]*s[m]
        int kg = idx >> 9, m = (idx >> 3) & 63, j = idx & 7;
        float s = gamma[m] * rsqrtf(var[m] + 1e-5f);
        w1pk[idx] = f2bf(w1[m * 256 + kg * 8 + j] * s);
    } else if (idx < 16448) {            // b1
        int o = idx - 16384;
        float s = gamma[o] * rsqrtf(var[o] + 1e-5f);
        b1[o] = beta[o] - mean[o] * s;
    } else if (idx < 81984) {            // w2gpk[g][kg][m][j] = w2[(g*49+m)][kg*8+j]
        int i = idx - 16448;
        int g = i >> 12, kg = (i >> 9) & 7, m = (i >> 3) & 63, j = i & 7;
        w2gpk[i] = (m < 49) ? f2bf(w2[(g * 49 + m) * 64 + kg * 8 + j]) : (u16)0;
    } else if (idx < 147520) {           // wppk[kg][m][j] = wp[m][kg*8+j]
        int i = idx - 81984;
        int kg = i >> 11, m = (i >> 3) & 255, j = i & 7;
        wppk[i] = f2bf(wp[m * 256 + kg * 8 + j]);
    }
}

// ---------------------------------------------------------------------------
// Stage 1 MFMA GEMM: y = relu(BN(w1 @ x)); K=256, M=64, output k-packed bf16.
// ---------------------------------------------------------------------------
__global__ __launch_bounds__(256) void gemm1m_k(
    const u16* __restrict__ xpk, const u16* __restrict__ w1pk,
    const float* __restrict__ b1, u16* __restrict__ ypk)
{
    __shared__ u16 Ws[32 * 64 * 8];
    __shared__ u16 As[2][8 * 64 * 8];

    const int t = threadIdx.x, lane = t & 63, wave = t >> 6;
    const int b = blockIdx.y, n0 = blockIdx.x * 64;
    const int ln = lane & 15, lk = lane >> 4;
    const u16* Ab = xpk + (size_t)b * 32 * 4096 * 8;

    for (int s = t; s < 2048; s += 256) {
        int kg = s >> 6, m = s & 63;
        uint4 v = *reinterpret_cast<const uint4*>(&w1pk[(size_t)s * 8]);
        *reinterpret_cast<uint4*>(&Ws[((kg * 64) + (m ^ (kg & 7))) * 8]) = v;
    }
    uint4 rs[2];
#pragma unroll
    for (int r = 0; r < 2; ++r) {
        int s = r * 256 + t, kg = s >> 6, nn = s & 63;
        rs[r] = *reinterpret_cast<const uint4*>(&Ab[((size_t)kg * 4096 + n0 + nn) * 8]);
    }
#pragma unroll
    for (int r = 0; r < 2; ++r) {
        int s = r * 256 + t, kg = s >> 6, nn = s & 63;
        *reinterpret_cast<uint4*>(&As[0][((kg * 64) + (nn ^ kg)) * 8]) = rs[r];
    }
    __syncthreads();

    f32x4 acc[4];
#pragma unroll
    for (int i = 0; i < 4; ++i)
#pragma unroll
        for (int e = 0; e < 4; ++e) acc[i][e] = 0.f;

    for (int ks = 0; ks < 4; ++ks) {
        const int cur = ks & 1;
        if (ks < 3) {
#pragma unroll
            for (int r = 0; r < 2; ++r) {
                int s = r * 256 + t, kg = s >> 6, nn = s & 63;
                rs[r] = *reinterpret_cast<const uint4*>(
                    &Ab[(((size_t)(ks + 1) * 8 + kg) * 4096 + n0 + nn) * 8]);
            }
        }
#pragma unroll
        for (int k32 = 0; k32 < 2; ++k32) {
            const int kgl = k32 * 4 + lk;
            const int kgw = ks * 8 + kgl;
            bf16x8 a[4];
#pragma unroll
            for (int i = 0; i < 4; ++i) {
                int n = i * 16 + ln;
                a[i] = *reinterpret_cast<const bf16x8*>(
                    &As[cur][((kgl * 64) + (n ^ kgl)) * 8]);
            }
            const int m = wave * 16 + ln;
            const bf16x8 bfr = *reinterpret_cast<const bf16x8*>(
                &Ws[((kgw * 64) + (m ^ (kgw & 7))) * 8]);
#pragma unroll
            for (int i = 0; i < 4; ++i)
                acc[i] = __builtin_amdgcn_mfma_f32_16x16x32_bf16(a[i], bfr, acc[i], 0, 0, 0);
        }
        if (ks < 3) {
#pragma unroll
            for (int r = 0; r < 2; ++r) {
                int s = r * 256 + t, kg = s >> 6, nn = s & 63;
                *reinterpret_cast<uint4*>(
                    &As[cur ^ 1][((kg * 64) + (nn ^ kg)) * 8]) = rs[r];
            }
            __syncthreads();
        }
    }

    const int m = wave * 16 + ln;
    const float bv = b1[m];
    u16* yb = ypk + ((size_t)b * 8 + (m >> 3)) * 4096 * 8 + (m & 7);
#pragma unroll
    for (int i = 0; i < 4; ++i) {
        const int n = n0 + i * 16 + lk * 4;
#pragma unroll
        for (int r = 0; r < 4; ++r)
            yb[(size_t)(n + r) * 8] = f2bf(fmaxf(acc[i][r] + bv, 0.f));
    }
}

// ---------------------------------------------------------------------------
// Fused weight-gen + involution. Block = (16x16 tile, group, batch).
// Phase 1 (MFMA): wt[256px][49kk] = y[256px][64k] @ w2g[64k][49kk] + b2,
//   written to LDS as fp16 [49][260].
// Phase 2 (VALU): out[px][16ch] = sum_kk wt[kk][px] * xpatch fp16 planes.
// ---------------------------------------------------------------------------
__global__ __launch_bounds__(256, 2) void fusedinv_k(
    const u16* __restrict__ ypk, const u16* __restrict__ w2gpk,
    const float* __restrict__ b2, const u16* __restrict__ xpk,
    u16* __restrict__ invpk)
{
    __shared__ alignas(16) char Lds[66560];
    u16* As = (u16*)Lds;                   // phase1: [8][256][8] bf16, 32 KB
    u16* Ws = (u16*)(Lds + 32768);         // phase1: [8][64][8] bf16, 8 KB
    _Float16* xs = (_Float16*)Lds;         // phase2: [2][484][8] f16, 15.5 KB
    u16* wt16 = (u16*)(Lds + 40960);       // [49][260] f16, 25.5 KB

    const int t = threadIdx.x, lane = t & 63, wave = t >> 6;
    const int tile = blockIdx.x, g = blockIdx.y, b = blockIdx.z;
    const int ty0 = (tile >> 2) * 16, tx0 = (tile & 3) * 16;
    const int ln = lane & 15, lk = lane >> 4;

    // ---- phase 1 staging: y tile (8kg x 256px) + w2 group slice
    const u16* yb = ypk + (size_t)b * 8 * 4096 * 8;
#pragma unroll
    for (int r = 0; r < 8; ++r) {
        int s = r * 256 + t;               // s = kg*256 + n
        int kg = s >> 8, n = s & 255;
        int gpix = (ty0 + (n >> 4)) * 64 + tx0 + (n & 15);
        *reinterpret_cast<uint4*>(&As[(size_t)s * 8]) =
            *reinterpret_cast<const uint4*>(&yb[((size_t)kg * 4096 + gpix) * 8]);
    }
#pragma unroll
    for (int r = 0; r < 2; ++r) {
        int s = r * 256 + t;               // s = kg*64 + m
        *reinterpret_cast<uint4*>(&Ws[(size_t)s * 8]) =
            *reinterpret_cast<const uint4*>(&w2gpk[((size_t)g * 512 + s) * 8]);
    }
    __syncthreads();

    // ---- phase 1 MFMA: wave owns m-slice [wave*16, wave*16+16)
    f32x4 acc[16];
#pragma unroll
    for (int i = 0; i < 16; ++i)
#pragma unroll
        for (int e = 0; e < 4; ++e) acc[i][e] = 0.f;

#pragma unroll
    for (int k32 = 0; k32 < 2; ++k32) {
        const int kg = k32 * 4 + lk;
        const bf16x8 wf = *reinterpret_cast<const bf16x8*>(
            &Ws[((kg * 64) + wave * 16 + ln) * 8]);
#pragma unroll
        for (int i = 0; i < 16; ++i) {
            const bf16x8 af = *reinterpret_cast<const bf16x8*>(
                &As[((kg * 256) + i * 16 + ln) * 8]);
            acc[i] = __builtin_amdgcn_mfma_f32_16x16x32_bf16(af, wf, acc[i], 0, 0, 0);
        }
    }
    __syncthreads();   // all As/Ws reads done; region A is reusable

    // ---- epilogue: wt -> LDS fp16 (region B)
    const int m = wave * 16 + ln;          // kk index
    if (m < 49) {
        const float bv = b2[g * 49 + m];
#pragma unroll
        for (int i = 0; i < 16; ++i) {
            u16 h0 = f2h(acc[i][0] + bv), h1 = f2h(acc[i][1] + bv);
            u16 h2 = f2h(acc[i][2] + bv), h3 = f2h(acc[i][3] + bv);
            uint2 v;
            v.x = (u32)h0 | ((u32)h1 << 16);
            v.y = (u32)h2 | ((u32)h3 << 16);
            *reinterpret_cast<uint2*>(&wt16[m * 260 + i * 16 + lk * 4]) = v;
        }
    }

    // ---- x patch staging: xpk bf16 -> xs fp16, 2 planes of 8 ch
    const u16* xb = xpk + ((size_t)b * 32 + g * 2) * 4096 * 8;
    for (int idx = t; idx < 968; idx += 256) {
        int plane = idx & 1, sp = idx >> 1;
        int sy = sp / 22, sx = sp - sy * 22;
        int gy = ty0 + sy - 3, gx = tx0 + sx - 3;
        uint4 v = {0u, 0u, 0u, 0u};
        if ((unsigned)gy < 64u && (unsigned)gx < 64u)
            v = *reinterpret_cast<const uint4*>(
                &xb[((size_t)plane * 4096 + gy * 64 + gx) * 8]);
        uint4 h;
        h.x = bfpair_to_h2(v.x); h.y = bfpair_to_h2(v.y);
        h.z = bfpair_to_h2(v.z); h.w = bfpair_to_h2(v.w);
        *reinterpret_cast<uint4*>(&xs[((size_t)plane * 484 + sp) * 8]) = h;
    }
    __syncthreads();

    // ---- phase 2: involution
    const int py = t >> 4, px = t & 15;
    float o[16];
#pragma unroll
    for (int i = 0; i < 16; ++i) o[i] = 0.f;

    for (int dy = 0; dy < 7; ++dy) {
        const int rowb = (py + dy) * 22 + px;
#pragma unroll
        for (int dx = 0; dx < 7; ++dx) {
            const int kk = dy * 7 + dx;
            const float wf = (float)__builtin_bit_cast(_Float16, wt16[kk * 260 + t]);
            const int sp = rowb + dx;
            const h16x8 x0 = *reinterpret_cast<const h16x8*>(&xs[(size_t)sp * 8]);
            const h16x8 x1 = *reinterpret_cast<const h16x8*>(&xs[((size_t)484 + sp) * 8]);
#pragma unroll
            for (int c = 0; c < 8; ++c) {
                o[c]     += wf * (float)x0[c];
                o[8 + c] += wf * (float)x1[c];
            }
        }
    }

    const int pix = (ty0 + py) * 64 + tx0 + px;
#pragma unroll
    for (int h = 0; h < 2; ++h) {
        u16 p[8];
#pragma unroll
        for (int j = 0; j < 8; ++j) p[j] = f2bf(o[h * 8 + j]);
        uint4 v;
        v.x = (u32)p[0] | ((u32)p[1] << 16);
        v.y = (u32)p[2] | ((u32)p[3] << 16);
        v.z = (u32)p[4] | ((u32)p[5] << 16);
        v.w = (u32)p[6] | ((u32)p[7] << 16);
        *reinterpret_cast<uint4*>(
            &invpk[(((size_t)b * 32 + g * 2 + h) * 4096 + pix) * 8]) = v;
    }
}

// ---------------------------------------------------------------------------
// Final MFMA GEMM: out[n][m] = sum_k inv[n][k] * wp[k][m]; K=M=256, fp32 out.
// ---------------------------------------------------------------------------
template<int K, int MP, bool OUT_BF16>
__global__ __launch_bounds__(256) void mgemm_k(
    const u16* __restrict__ Apk,
    const u16* __restrict__ Wpk,
    const float* __restrict__ bias,
    void* __restrict__ Cout,
    int Mout)
{
    constexpr int NK = K / 64;
    constexpr int DB = (NK > 1) ? 2 : 1;
    __shared__ u16 As[DB][8 * 128 * 8];
    __shared__ u16 Ws[(K / 8) * 64 * 8];

    const int t = threadIdx.x;
    const int lane = t & 63, wave = t >> 6;
    const int m0 = blockIdx.x * 64;
    const int batch = blockIdx.y >> 5;
    const int n0 = (blockIdx.y & 31) * 128;
    const u16* Ab = Apk + (size_t)batch * (K / 8) * 4096 * 8;

    const int n0w = (wave & 1) * 64;
    const int m0w = (wave >> 1) * 32;
    const int ln = lane & 15, lk = lane >> 4;

    for (int s = t; s < (K / 8) * 64; s += 256) {
        int kg = s >> 6, m = s & 63;
        const uint4 v = *reinterpret_cast<const uint4*>(
            &Wpk[((size_t)kg * MP + m0 + m) * 8]);
        *reinterpret_cast<uint4*>(&Ws[((size_t)kg * 64 + (m ^ (kg & 7))) * 8]) = v;
    }

    uint4 rs[4];
#pragma unroll
    for (int r = 0; r < 4; ++r) {
        int s = r * 256 + t, kg = s >> 7, nn = s & 127;
        rs[r] = *reinterpret_cast<const uint4*>(&Ab[((size_t)kg * 4096 + n0 + nn) * 8]);
    }
#pragma unroll
    for (int r = 0; r < 4; ++r) {
        int s = r * 256 + t, kg = s >> 7, nn = s & 127;
        *reinterpret_cast<uint4*>(&As[0][((size_t)kg * 128 + (nn ^ kg)) * 8]) = rs[r];
    }
    __syncthreads();

    f32x4 acc[4][2];
#pragma unroll
    for (int i = 0; i < 4; ++i)
#pragma unroll
        for (int f = 0; f < 2; ++f)
#pragma unroll
            for (int e = 0; e < 4; ++e) acc[i][f][e] = 0.f;

    for (int ks = 0; ks < NK; ++ks) {
        const int cur = ks & (DB - 1);
        if (ks + 1 < NK) {
#pragma unroll
            for (int r = 0; r < 4; ++r) {
                int s = r * 256 + t, kg = s >> 7, nn = s & 127;
                rs[r] = *reinterpret_cast<const uint4*>(
                    &Ab[(((size_t)(ks + 1) * 8 + kg) * 4096 + n0 + nn) * 8]);
            }
        }
#pragma unroll
        for (int k32 = 0; k32 < 2; ++k32) {
            const int kg = k32 * 4 + lk;
            bf16x8 a[4], bfr[2];
#pragma unroll
            for (int i = 0; i < 4; ++i) {
                int n = n0w + i * 16 + ln;
                a[i] = *reinterpret_cast<const bf16x8*>(
                    &As[cur][((size_t)kg * 128 + (n ^ kg)) * 8]);
            }
            const int kgw = ks * 8 + kg;
#pragma unroll
            for (int f = 0; f < 2; ++f) {
                int m = m0w + f * 16 + ln;
                bfr[f] = *reinterpret_cast<const bf16x8*>(
                    &Ws[((size_t)kgw * 64 + (m ^ (kgw & 7))) * 8]);
            }
#pragma unroll
            for (int i = 0; i < 4; ++i)
#pragma unroll
                for (int f = 0; f < 2; ++f)
                    acc[i][f] = __builtin_amdgcn_mfma_f32_16x16x32_bf16(
                        a[i], bfr[f], acc[i][f], 0, 0, 0);
        }
        if (ks + 1 < NK) {
#pragma unroll
            for (int r = 0; r < 4; ++r) {
                int s = r * 256 + t, kg = s >> 7, nn = s & 127;
                *reinterpret_cast<uint4*>(
                    &As[cur ^ 1][((size_t)kg * 128 + (nn ^ kg)) * 8]) = rs[r];
            }
            __syncthreads();
        }
    }

#pragma unroll
    for (int f = 0; f < 2; ++f) {
        const int m = m0 + m0w + f * 16 + ln;
        if (m < Mout) {
#pragma unroll
            for (int i = 0; i < 4; ++i) {
                const int n = n0 + n0w + i * 16 + lk * 4;
                const size_t off = ((size_t)batch * Mout + m) * 4096 + n;
                if (OUT_BF16) {
                    const float bv = bias[m];
                    u16 p[4];
#pragma unroll
                    for (int r = 0; r < 4; ++r) p[r] = f2bf(acc[i][f][r] + bv);
                    uint2 v;
                    v.x = (u32)p[0] | ((u32)p[1] << 16);
                    v.y = (u32)p[2] | ((u32)p[3] << 16);
                    *reinterpret_cast<uint2*>(&((u16*)Cout)[off]) = v;
                } else {
                    float4 v = {acc[i][f][0], acc[i][f][1], acc[i][f][2], acc[i][f][3]};
                    *reinterpret_cast<float4*>(&((float*)Cout)[off]) = v;
                }
            }
        }
    }
}

// ---------------------------------------------------------------------------
extern "C" void kernel_launch(void* const* d_in, const int* in_sizes, int n_in,
                              void* d_out, int out_size, void* d_ws, size_t ws_size,
                              hipStream_t stream)
{
    const float* x     = (const float*)d_in[0];
    const float* w1    = (const float*)d_in[1];
    const float* gamma = (const float*)d_in[2];
    const float* beta  = (const float*)d_in[3];
    const float* mean  = (const float*)d_in[4];
    const float* var   = (const float*)d_in[5];
    const float* w2    = (const float*)d_in[6];
    const float* b2    = (const float*)d_in[7];
    const float* wp    = (const float*)d_in[8];
    float* out = (float*)d_out;
    float* ws  = (float*)d_ws;

    float* b1 = ws;                 // 64 floats
    u16* u = (u16*)(ws + 64);
    u16* w1pk  = u;                 // 16384
    u16* w2gpk = u + 16384;         // 65536
    u16* wppk  = u + 81920;         // 65536
    u16* xpk   = u + 147456;        // 4*32*4096*8 = 4194304
    u16* ypk   = u + 4341760;       // 4*8*4096*8  = 1048576
    u16* invpk = u + 5390336;       // 4*32*4096*8 = 4194304
                                    // total ~19.2 MB

    prep2_k<<<2625, 256, 0, stream>>>(x, w1, gamma, beta, mean, var, w2, wp,
                                      xpk, w1pk, b1, w2gpk, wppk);
    // y = relu(BN(w1 @ x)) -> k-packed bf16
    gemm1m_k<<<dim3(64, 4), 256, 0, stream>>>(xpk, w1pk, b1, ypk);
    // fused: wt = w2g @ y + b2 (MFMA, in-LDS) ; inv = involution(x, wt)
    fusedinv_k<<<dim3(16, 16, 4), 256, 0, stream>>>(ypk, w2gpk, b2, xpk, invpk);
    // out = wp @ inv  (K=256, M=256) -> fp32
    mgemm_k<256, 256, false><<<dim3(4, 128), 256, 0, stream>>>(
        invpk, wppk, nullptr, (void*)out, 256);
}